// Round 11
// baseline (943.129 us; speedup 1.0000x reference)
//
#include <hip/hip_runtime.h>
#include <hip/hip_bf16.h>
#include <cstdint>

// AttnLayerBU round 11: mega3 = 2 leaf tiles per block (shared B-frags: 16
// MFMA per 8 LDS reads, staging+barriers per work halved). r8 dbuf pipeline,
// r9 strides. 79104 B dyn LDS -> 2 blocks/CU. Aux + epilogue unchanged.

#define DIM 256
#define NH 8
#define HD 32

static constexpr float SCALE = 0.17677669529663687f; // 32^-0.5

typedef __bf16 bf16x8 __attribute__((ext_vector_type(8)));
typedef __bf16 bf16x4 __attribute__((ext_vector_type(4)));
typedef float  f32x4  __attribute__((ext_vector_type(4)));

__device__ __forceinline__ float dot4(const float4 a, const float4 b) {
    return a.x * b.x + a.y * b.y + a.z * b.z + a.w * b.w;
}

// ---------------------------------------------------------------------------
__global__ __launch_bounds__(256) void cvt_f2b(const float* __restrict__ s,
                                               __bf16* __restrict__ d, int n) {
    int i = (blockIdx.x * 256 + threadIdx.x) * 4;
    if (i < n) {
        float4 v = *(const float4*)(s + i);
        d[i + 0] = (__bf16)v.x; d[i + 1] = (__bf16)v.y;
        d[i + 2] = (__bf16)v.z; d[i + 3] = (__bf16)v.w;
    }
}

// ---------------------------------------------------------------------------
// mega3: block = (tile-pair, head-pair). 4096 blocks. LDS 79104 B:
//   Qs0@0      [64][80]  | Pw0 overlay       Qs1@29696 [64][80] | Pw1
//   Ks0@10240  [64][80]  | K4t0 overlay      Ks1@39936 [64][80] | K4t1
//   Vt0@20480  [64][72]  | V4t0 overlay      Vt1@50176 [64][72] | V4t1
//   Bs[2][16][272]@59392 (17408)   scratch@76800 (2304)
// ---------------------------------------------------------------------------
__device__ void mega3_body(int g,
    const float* __restrict__ X, const float* __restrict__ inner,
    const __bf16* __restrict__ W1b, const float* __restrict__ Bi1,
    const __bf16* __restrict__ W4kvb, const float* __restrict__ W4q,
    const float* __restrict__ Bi4, __bf16* __restrict__ O1,
    float* __restrict__ Oc, char* __restrict__ smem)
{
    const int xcd  = g & 7;
    const int idx  = g >> 3;               // 0..511
    const int pair = xcd * 128 + (idx >> 2);   // 0..1023 (tile pair)
    const int hg   = idx & 3;              // head-pair: heads 2hg, 2hg+1
    const int tid  = threadIdx.x;
    const int wid  = tid >> 6;             // 0..3
    const int lane = tid & 63;
    const int lr   = lane & 15;
    const int lk   = (lane >> 4) * 8;
    const int prow = (lane >> 4) * 4;
    const int tok0 = wid * 16 + prow;

    __bf16* QsA[2] = { (__bf16*)smem,           (__bf16*)(smem + 29696) };
    __bf16* KsA[2] = { (__bf16*)(smem + 10240), (__bf16*)(smem + 39936) };
    __bf16* VtA[2] = { (__bf16*)(smem + 20480), (__bf16*)(smem + 50176) };
    __bf16* Bs0 = (__bf16*)(smem + 59392);
    __bf16* Bs1 = (__bf16*)(smem + 68096);
    float* qpart = (float*)(smem + 76800);          // [4][64]
    float* qv    = qpart + 256;                     // [64]
    float* psm   = qv + 64;                         // [2][64]
    float* opart = psm + 128;                       // [2][64]

    // ---- A-fragments for both tiles (wave wid owns rows wid*16..+15) ----
    bf16x8 a0[8], a1[8];
#pragma unroll
    for (int j = 0; j < 2; ++j) {
        const float* xrow = X + ((size_t)pair * 128 + j * 64 + wid * 16 + lr) * DIM + lk;
#pragma unroll
        for (int k = 0; k < 8; ++k) {
            float4 v0 = *(const float4*)(xrow + k * 32);
            float4 v1 = *(const float4*)(xrow + k * 32 + 4);
            bf16x8 t;
            t[0] = (__bf16)v0.x; t[1] = (__bf16)v0.y; t[2] = (__bf16)v0.z; t[3] = (__bf16)v0.w;
            t[4] = (__bf16)v1.x; t[5] = (__bf16)v1.y; t[6] = (__bf16)v1.z; t[7] = (__bf16)v1.w;
            if (j == 0) a0[k] = t; else a1[k] = t;
        }
    }

    // ---- inner_c q-projection partials for tile 0 (overlaps phase 1) ----
    {
        const int o = tid & 63, part = tid >> 6;
        const float4* wr = (const float4*)(W4q + (size_t)(hg * 64 + o) * DIM + part * 64);
        const float4* xr = (const float4*)(inner + (size_t)(pair * 2) * DIM + part * 64);
        float accq = 0.f;
#pragma unroll
        for (int k = 0; k < 16; ++k) accq += dot4(xr[k], wr[k]);
        qpart[part * 64 + o] = accq;
    }

    const int srow = tid >> 5;              // 0..7
    const int scol = (tid & 31) * 8;        // bf16 elems

    // ---- Phase 1: tiles 0..11 (W1 Q/K/V), double-buffered Bs ----
    {
        auto wsrc = [&](int t) -> const __bf16* {
            const int sec = t >> 2, sub = t & 3;
            return W1b + (size_t)(sec * 256 + hg * 64 + sub * 16) * DIM;
        };
        {   // prologue: tile 0 -> Bs0
            const __bf16* p = wsrc(0);
            bf16x8 g0 = *(const bf16x8*)(p + (size_t)srow * DIM + scol);
            bf16x8 g1 = *(const bf16x8*)(p + (size_t)(8 + srow) * DIM + scol);
            *(bf16x8*)(Bs0 + srow * 272 + scol) = g0;
            *(bf16x8*)(Bs0 + (8 + srow) * 272 + scol) = g1;
        }
        __syncthreads();
        for (int t = 0; t < 12; ++t) {
            const __bf16* Bc = (t & 1) ? Bs1 : Bs0;
            __bf16*       Bn = (t & 1) ? Bs0 : Bs1;
            bf16x8 g0, g1;
            if (t + 1 < 12) {
                const __bf16* p = wsrc(t + 1);
                g0 = *(const bf16x8*)(p + (size_t)srow * DIM + scol);
                g1 = *(const bf16x8*)(p + (size_t)(8 + srow) * DIM + scol);
            }
            f32x4 c0L = {0.f,0.f,0.f,0.f}, c0H = {0.f,0.f,0.f,0.f};
            f32x4 c1L = {0.f,0.f,0.f,0.f}, c1H = {0.f,0.f,0.f,0.f};
#pragma unroll
            for (int kk = 0; kk < 4; ++kk) {
                const bf16x8 bL = *(const bf16x8*)(Bc + lr * 272 + kk * 32 + lk);
                c0L = __builtin_amdgcn_mfma_f32_16x16x32_bf16(a0[kk], bL, c0L, 0, 0, 0);
                c1L = __builtin_amdgcn_mfma_f32_16x16x32_bf16(a1[kk], bL, c1L, 0, 0, 0);
            }
#pragma unroll
            for (int kk = 0; kk < 4; ++kk) {
                const bf16x8 bH = *(const bf16x8*)(Bc + lr * 272 + (kk + 4) * 32 + lk);
                c0H = __builtin_amdgcn_mfma_f32_16x16x32_bf16(a0[kk + 4], bH, c0H, 0, 0, 0);
                c1H = __builtin_amdgcn_mfma_f32_16x16x32_bf16(a1[kk + 4], bH, c1H, 0, 0, 0);
            }
            f32x4 accT[2] = { c0L + c0H, c1L + c1H };
            const int sub = t & 3;
            const int col = sub * 16 + lr;
#pragma unroll
            for (int j = 0; j < 2; ++j) {
                const f32x4 acc = accT[j];
                if (t < 4) {
                    const float bias = Bi1[hg * 64 + sub * 16 + lr];
#pragma unroll
                    for (int r = 0; r < 4; ++r)
                        QsA[j][(size_t)(tok0 + r) * 80 + col] = (__bf16)((acc[r] + bias) * SCALE);
                } else if (t < 8) {
                    const float bias = Bi1[256 + hg * 64 + sub * 16 + lr];
#pragma unroll
                    for (int r = 0; r < 4; ++r)
                        KsA[j][(size_t)(tok0 + r) * 80 + col] = (__bf16)(acc[r] + bias);
                } else {
                    const float bias = Bi1[512 + hg * 64 + sub * 16 + lr];
                    bf16x4 pv;
#pragma unroll
                    for (int r = 0; r < 4; ++r) pv[r] = (__bf16)(acc[r] + bias);
                    *(bf16x4*)(VtA[j] + (size_t)col * 72 + tok0) = pv;
                }
            }
            if (t + 1 < 12) {
                *(bf16x8*)(Bn + srow * 272 + scol) = g0;
                *(bf16x8*)(Bn + (8 + srow) * 272 + scol) = g1;
            }
            __syncthreads();
        }
    }

    // ---- leaf_s attention per tile: wave = (head hh, q-half qh) ----
    const int hh = wid >> 1;
    const int qh = wid & 1;
#pragma unroll
    for (int j = 0; j < 2; ++j) {
        __bf16* Qs = QsA[j];
        __bf16* Ks = KsA[j];
        __bf16* Vt = VtA[j];
        __bf16* Pw = Qs + wid * 1280;           // overlay: wave rows of Qs
        f32x4 s[2][4];
        {
            bf16x8 kb[4];
#pragma unroll
            for (int kt = 0; kt < 4; ++kt)
                kb[kt] = *(const bf16x8*)(Ks + (size_t)(kt * 16 + lr) * 80 + hh * 32 + lk);
#pragma unroll
            for (int q2 = 0; q2 < 2; ++q2) {
                const int qt = qh * 2 + q2;
                const bf16x8 qa = *(const bf16x8*)(Qs + (size_t)(qt * 16 + lr) * 80 + hh * 32 + lk);
#pragma unroll
                for (int kt = 0; kt < 4; ++kt) {
                    f32x4 z = {0.f, 0.f, 0.f, 0.f};
                    s[q2][kt] = __builtin_amdgcn_mfma_f32_16x16x32_bf16(qa, kb[kt], z, 0, 0, 0);
                }
            }
        }
#pragma unroll
        for (int q2 = 0; q2 < 2; ++q2) {
#pragma unroll
            for (int r = 0; r < 4; ++r) {
                float m = fmaxf(fmaxf(s[q2][0][r], s[q2][1][r]), fmaxf(s[q2][2][r], s[q2][3][r]));
#pragma unroll
                for (int off = 1; off < 16; off <<= 1) m = fmaxf(m, __shfl_xor(m, off));
                const float p0 = __expf(s[q2][0][r] - m), p1 = __expf(s[q2][1][r] - m);
                const float p2 = __expf(s[q2][2][r] - m), p3 = __expf(s[q2][3][r] - m);
                float t = p0 + p1 + p2 + p3;
#pragma unroll
                for (int off = 1; off < 16; off <<= 1) t += __shfl_xor(t, off);
                const float inv = 1.0f / t;
                s[q2][0][r] = p0 * inv; s[q2][1][r] = p1 * inv;
                s[q2][2][r] = p2 * inv; s[q2][3][r] = p3 * inv;
            }
        }
        bf16x8 vb[2][2];
#pragma unroll
        for (int dt = 0; dt < 2; ++dt)
#pragma unroll
            for (int ks = 0; ks < 2; ++ks)
                vb[dt][ks] = *(const bf16x8*)(Vt + (size_t)(hh * 32 + dt * 16 + lr) * 72 + ks * 32 + lk);
        __syncthreads();                        // all reads of this tile done

        // PV
#pragma unroll
        for (int q2 = 0; q2 < 2; ++q2) {
            const int qt = qh * 2 + q2;
#pragma unroll
            for (int kt = 0; kt < 4; ++kt)
#pragma unroll
                for (int r = 0; r < 4; ++r)
                    Pw[(size_t)(prow + r) * 80 + kt * 16 + lr] = (__bf16)s[q2][kt][r];
            bf16x8 pa[2];
#pragma unroll
            for (int ks = 0; ks < 2; ++ks)
                pa[ks] = *(const bf16x8*)(Pw + (size_t)lr * 80 + ks * 32 + lk);
#pragma unroll
            for (int dt = 0; dt < 2; ++dt) {
                f32x4 o = {0.f, 0.f, 0.f, 0.f};
#pragma unroll
                for (int ks = 0; ks < 2; ++ks)
                    o = __builtin_amdgcn_mfma_f32_16x16x32_bf16(pa[ks], vb[dt][ks], o, 0, 0, 0);
                const int colO = (hg * 2 + hh) * 32 + dt * 16 + lr;
#pragma unroll
                for (int r = 0; r < 4; ++r)
                    O1[((size_t)pair * 128 + j * 64 + qt * 16 + prow + r) * DIM + colO] = (__bf16)o[r];
            }
        }
        if (j == 0) __syncthreads();            // PV0 Pw traffic is wave-local; sync before tile1? (cheap safety)
    }

    // ---- Phase 2 prologue: stage tile 12 -> Bs0 (Bs free since phase 1) ----
    {
        const __bf16* p = W4kvb + (size_t)(hg * 64) * DIM;
        bf16x8 g0 = *(const bf16x8*)(p + (size_t)srow * DIM + scol);
        bf16x8 g1 = *(const bf16x8*)(p + (size_t)(8 + srow) * DIM + scol);
        *(bf16x8*)(Bs0 + srow * 272 + scol) = g0;
        *(bf16x8*)(Bs0 + (8 + srow) * 272 + scol) = g1;
    }
    __syncthreads();                            // PV1 done + Bs0 ready (K/V overlays now writable)

    // ---- Phase 2: tiles 12..19 (W4 K/V) -> K4t/V4t overlays, dbuf ----
    {
        auto wsrc = [&](int t) -> const __bf16* {
            const int u = t - 12, sec = u >> 2, sub = t & 3;
            return W4kvb + (size_t)(sec * 256 + hg * 64 + sub * 16) * DIM;
        };
        for (int t = 12; t < 20; ++t) {
            const __bf16* Bc = (t & 1) ? Bs1 : Bs0;
            __bf16*       Bn = (t & 1) ? Bs0 : Bs1;
            bf16x8 g0, g1;
            if (t + 1 < 20) {
                const __bf16* p = wsrc(t + 1);
                g0 = *(const bf16x8*)(p + (size_t)srow * DIM + scol);
                g1 = *(const bf16x8*)(p + (size_t)(8 + srow) * DIM + scol);
            }
            f32x4 c0L = {0.f,0.f,0.f,0.f}, c0H = {0.f,0.f,0.f,0.f};
            f32x4 c1L = {0.f,0.f,0.f,0.f}, c1H = {0.f,0.f,0.f,0.f};
#pragma unroll
            for (int kk = 0; kk < 4; ++kk) {
                const bf16x8 bL = *(const bf16x8*)(Bc + lr * 272 + kk * 32 + lk);
                c0L = __builtin_amdgcn_mfma_f32_16x16x32_bf16(a0[kk], bL, c0L, 0, 0, 0);
                c1L = __builtin_amdgcn_mfma_f32_16x16x32_bf16(a1[kk], bL, c1L, 0, 0, 0);
            }
#pragma unroll
            for (int kk = 0; kk < 4; ++kk) {
                const bf16x8 bH = *(const bf16x8*)(Bc + lr * 272 + (kk + 4) * 32 + lk);
                c0H = __builtin_amdgcn_mfma_f32_16x16x32_bf16(a0[kk + 4], bH, c0H, 0, 0, 0);
                c1H = __builtin_amdgcn_mfma_f32_16x16x32_bf16(a1[kk + 4], bH, c1H, 0, 0, 0);
            }
            f32x4 accT[2] = { c0L + c0H, c1L + c1H };
            const int sub = t & 3;
            const int col = sub * 16 + lr;
#pragma unroll
            for (int j = 0; j < 2; ++j) {
                const f32x4 acc = accT[j];
                bf16x4 pv;
                if (t < 16) {                   // K4 -> Ks overlay, stride 80
                    const float bias = Bi4[256 + hg * 64 + sub * 16 + lr];
#pragma unroll
                    for (int r = 0; r < 4; ++r) pv[r] = (__bf16)(acc[r] + bias);
                    *(bf16x4*)(KsA[j] + (size_t)col * 80 + tok0) = pv;
                } else {                        // V4 -> Vt overlay, stride 72
                    const float bias = Bi4[512 + hg * 64 + sub * 16 + lr];
#pragma unroll
                    for (int r = 0; r < 4; ++r) pv[r] = (__bf16)(acc[r] + bias);
                    *(bf16x4*)(VtA[j] + (size_t)col * 72 + tok0) = pv;
                }
            }
            if (t + 1 < 20) {
                *(bf16x8*)(Bn + srow * 272 + scol) = g0;
                *(bf16x8*)(Bn + (8 + srow) * 272 + scol) = g1;
            }
            __syncthreads();
        }
    }

    // ---- inner_c per tile (sequential, shared scratch; qpart0 precomputed) ----
#pragma unroll
    for (int j = 0; j < 2; ++j) {
        if (tid < 64)
            qv[tid] = (qpart[tid] + qpart[64 + tid] + qpart[128 + tid] + qpart[192 + tid]
                       + Bi4[hg * 64 + tid]) * SCALE;
        __syncthreads();
        if (wid < 2) {
            const int jj = lane;
            float sv = 0.f;
#pragma unroll
            for (int d = 0; d < 32; ++d)
                sv += qv[wid * 32 + d] * (float)KsA[j][(size_t)(wid * 32 + d) * 80 + jj];
            float m = sv;
#pragma unroll
            for (int off = 1; off < 64; off <<= 1) m = fmaxf(m, __shfl_xor(m, off));
            const float p = __expf(sv - m);
            float t = p;
#pragma unroll
            for (int off = 1; off < 64; off <<= 1) t += __shfl_xor(t, off);
            psm[wid * 64 + jj] = p / t;
        }
        __syncthreads();
        if (tid < 128) {
            const int o = tid & 63, hf = tid >> 6;
            const int ho = o >> 5;
            float acc2 = 0.f;
#pragma unroll
            for (int jj = 0; jj < 32; ++jj)
                acc2 += psm[ho * 64 + hf * 32 + jj] * (float)VtA[j][(size_t)o * 72 + hf * 32 + jj];
            opart[hf * 64 + o] = acc2;
        }
        __syncthreads();
        if (tid < 64)
            Oc[(size_t)(pair * 2 + j) * DIM + hg * 64 + tid] = opart[tid] + opart[64 + tid];
        if (j == 0) {
            // qpart for tile 1 (disjoint from opart reads)
            const int o = tid & 63, part = tid >> 6;
            const float4* wr = (const float4*)(W4q + (size_t)(hg * 64 + o) * DIM + part * 64);
            const float4* xr = (const float4*)(inner + (size_t)(pair * 2 + 1) * DIM + part * 64);
            float accq = 0.f;
#pragma unroll
            for (int k = 0; k < 16; ++k) accq += dot4(xr[k], wr[k]);
            __syncthreads();                    // opart reads done before qpart overwrite? (opart!=qpart; safe ordering for qv read next iter)
            qpart[part * 64 + o] = accq;
            __syncthreads();
        }
    }
}

// ---------------------------------------------------------------------------
// leafp MFMA 2-stage, 32 rows/block (64 blocks). (r10 verbatim)
// ---------------------------------------------------------------------------
__device__ void leafp_mfma_body(int bid, const float* __restrict__ inner,
    const __bf16* __restrict__ Wv0b, const __bf16* __restrict__ Wo0b,
    const float* __restrict__ b_in0, const float* __restrict__ b_out0,
    float* __restrict__ tP, char* __restrict__ smem)
{
    __bf16* tV = (__bf16*)smem;             // [32][264]
    const int tid  = threadIdx.x;
    const int wid  = tid >> 6;
    const int lane = tid & 63;
    const int lr   = lane & 15;
    const int lk   = (lane >> 4) * 8;
    const int prow = (lane >> 4) * 4;
    const int rg   = wid & 1;
    const int ch   = wid >> 1;
    __bf16* Bsc = (__bf16*)(smem + 16896 + ch * 8704);
    const int l    = tid & 127;
    const int brow = l >> 3;
    const int bcol = (l & 7) * 32;

    bf16x8 a[8];
    {
        const float* xrow = inner + ((size_t)bid * 32 + rg * 16 + lr) * DIM + lk;
#pragma unroll
        for (int k = 0; k < 8; ++k) {
            float4 v0 = *(const float4*)(xrow + k * 32);
            float4 v1 = *(const float4*)(xrow + k * 32 + 4);
            bf16x8 t;
            t[0] = (__bf16)v0.x; t[1] = (__bf16)v0.y; t[2] = (__bf16)v0.z; t[3] = (__bf16)v0.w;
            t[4] = (__bf16)v1.x; t[5] = (__bf16)v1.y; t[6] = (__bf16)v1.z; t[7] = (__bf16)v1.w;
            a[k] = t;
        }
    }

    auto stage_tile = [&](const __bf16* W, int t) {
        const __bf16* p = W + (size_t)(t * 16 + brow) * DIM + bcol;
#pragma unroll
        for (int q = 0; q < 4; ++q)
            *(bf16x8*)(Bsc + brow * 272 + bcol + q * 8) = *(const bf16x8*)(p + q * 8);
    };

    stage_tile(Wv0b, ch * 8);
    __syncthreads();
    for (int i = 0; i < 8; ++i) {
        const int t = ch * 8 + i;
        f32x4 acc = {0.f, 0.f, 0.f, 0.f};
#pragma unroll
        for (int k = 0; k < 8; ++k)
            acc = __builtin_amdgcn_mfma_f32_16x16x32_bf16(
                a[k], *(const bf16x8*)(Bsc + lr * 272 + k * 32 + lk), acc, 0, 0, 0);
        const float bias = b_in0[512 + t * 16 + lr];
#pragma unroll
        for (int r = 0; r < 4; ++r)
            tV[(size_t)(rg * 16 + prow + r) * 264 + t * 16 + lr] = (__bf16)(acc[r] + bias);
        __syncthreads();
        if (i + 1 < 8) { stage_tile(Wv0b, t + 1); __syncthreads(); }
    }
    __syncthreads();

    bf16x8 a2[8];
#pragma unroll
    for (int k = 0; k < 8; ++k)
        a2[k] = *(const bf16x8*)(tV + (size_t)(rg * 16 + lr) * 264 + k * 32 + lk);
    __syncthreads();
    stage_tile(Wo0b, ch * 8);
    __syncthreads();
    for (int i = 0; i < 8; ++i) {
        const int t = ch * 8 + i;
        f32x4 acc = {0.f, 0.f, 0.f, 0.f};
#pragma unroll
        for (int k = 0; k < 8; ++k)
            acc = __builtin_amdgcn_mfma_f32_16x16x32_bf16(
                a2[k], *(const bf16x8*)(Bsc + lr * 272 + k * 32 + lk), acc, 0, 0, 0);
        const float bo = b_out0[t * 16 + lr];
#pragma unroll
        for (int r = 0; r < 4; ++r)
            tP[((size_t)bid * 32 + rg * 16 + prow + r) * DIM + t * 16 + lr] = acc[r] + bo;
        __syncthreads();
        if (i + 1 < 8) { stage_tile(Wo0b, t + 1); __syncthreads(); }
    }
}

// ---------------------------------------------------------------------------
// fp32 attention, Q projected per-chunk (r10 verbatim)
// ---------------------------------------------------------------------------
template <int LQ, int LK, int RQ>
__device__ void attn_body(int bx, const float* __restrict__ Xq,
                          const float* __restrict__ Xkv,
                          const float* __restrict__ Wi, const float* __restrict__ Bi,
                          float* __restrict__ O, float* __restrict__ sm)
{
    const int b   = bx >> 3;
    const int h   = bx & 7;
    const int tid = threadIdx.x;

    float* KsP = sm;
    float* VsP = KsP + LK * 33;
    float* QsP = VsP + LK * 33;
    float* SP  = QsP + RQ * 33;

    const float* xq  = Xq  + (size_t)b * LQ * DIM;
    const float* xkv = Xkv + (size_t)b * LK * DIM;

    {
        const int col   = tid & 63;
        const int which = col >> 5;
        const int d     = col & 31;
        const int row   = DIM + which * DIM + h * HD + d;
        const float4* wr = (const float4*)(Wi + (size_t)row * DIM);
        const float bias = Bi[row];
        constexpr int TT = LK / 4;
        float acc[TT];
#pragma unroll
        for (int i = 0; i < TT; ++i) acc[i] = 0.f;
        const int t0 = tid >> 6;
        for (int k4 = 0; k4 < DIM / 4; ++k4) {
            const float4 w = wr[k4];
#pragma unroll
            for (int i = 0; i < TT; ++i) {
                const int t = t0 + 4 * i;
                const float4 aa = ((const float4*)(xkv + (size_t)t * DIM))[k4];
                acc[i] += dot4(aa, w);
            }
        }
#pragma unroll
        for (int i = 0; i < TT; ++i) {
            const int t = t0 + 4 * i;
            if (which == 0) KsP[t * 33 + d] = acc[i] + bias;
            else            VsP[t * 33 + d] = acc[i] + bias;
        }
    }
    __syncthreads();

    for (int q0 = 0; q0 < LQ; q0 += RQ) {
        {
            const int d  = tid & 31;
            const int rg = tid >> 5;
            const int row = h * HD + d;
            const float4* wr = (const float4*)(Wi + (size_t)row * DIM);
            const float bias = Bi[row];
#pragma unroll
            for (int i = 0; i < RQ / 8; ++i) {
                const int rloc = rg + 8 * i;
                float acc = 0.f;
                const float4* xr = (const float4*)(xq + (size_t)(q0 + rloc) * DIM);
                for (int k4 = 0; k4 < DIM / 4; ++k4) acc += dot4(xr[k4], wr[k4]);
                QsP[rloc * 33 + d] = (acc + bias) * SCALE;
            }
        }
        __syncthreads();
        for (int idx = tid; idx < RQ * LK; idx += 256) {
            const int r = idx / LK;
            const int j = idx - r * LK;
            float acc = 0.f;
#pragma unroll
            for (int d = 0; d < HD; ++d)
                acc += QsP[r * 33 + d] * KsP[j * 33 + d];
            SP[r * (LK + 1) + j] = acc;
        }
        __syncthreads();
        if (tid < RQ * 8) {
            const int r   = tid >> 3;
            const int sub = tid & 7;
            float m = -1e30f;
            for (int j = sub; j < LK; j += 8) m = fmaxf(m, SP[r * (LK + 1) + j]);
#pragma unroll
            for (int off = 4; off; off >>= 1) m = fmaxf(m, __shfl_xor(m, off, 8));
            float sum = 0.f;
            for (int j = sub; j < LK; j += 8) {
                const float p = __expf(SP[r * (LK + 1) + j] - m);
                SP[r * (LK + 1) + j] = p;
                sum += p;
            }
#pragma unroll
            for (int off = 4; off; off >>= 1) sum += __shfl_xor(sum, off, 8);
            const float inv = 1.0f / sum;
            for (int j = sub; j < LK; j += 8) SP[r * (LK + 1) + j] *= inv;
        }
        __syncthreads();
        for (int idx = tid; idx < RQ * HD; idx += 256) {
            const int r = idx >> 5;
            const int d = idx & 31;
            float acc = 0.f;
            for (int j = 0; j < LK; ++j)
                acc += SP[r * (LK + 1) + j] * VsP[j * 33 + d];
            O[((size_t)(b * LQ + q0 + r)) * DIM + h * HD + d] = acc;
        }
        __syncthreads();
    }
}

// ---------------------------------------------------------------------------
// fused_main: aux first, then 4096 mega3 blocks. 79104 B -> 2 blocks/CU.
// ---------------------------------------------------------------------------
__global__ __launch_bounds__(256, 2) void fused_main(
    const float* __restrict__ leaf, const float* __restrict__ inner,
    const float* __restrict__ root,
    const float* __restrict__ w_in, const float* __restrict__ b_in,
    const float* __restrict__ b_out,
    const __bf16* __restrict__ W1b, const __bf16* __restrict__ W4kvb,
    const __bf16* __restrict__ Wv0b, const __bf16* __restrict__ Wo0b,
    __bf16* __restrict__ O1, float* __restrict__ Oc, float* __restrict__ tP,
    float* __restrict__ Op, float* __restrict__ Osf,
    float* __restrict__ Ors, float* __restrict__ Orc)
{
    extern __shared__ __align__(16) char smem[];
    const int bid = blockIdx.x;
    const size_t WI = 768 * 256, BI = 768;
    if (bid < 128)
        attn_body<128, 128, 16>(bid, inner, inner, w_in + 3 * WI, b_in + 3 * BI,
                                Osf, (float*)smem);
    else if (bid < 256)
        attn_body<16, 128, 16>(bid - 128, root, inner, w_in + 5 * WI, b_in + 5 * BI,
                               Orc, (float*)smem);
    else if (bid < 384)
        attn_body<128, 16, 32>(bid - 256, inner, root, w_in + 2 * WI, b_in + 2 * BI,
                               Op, (float*)smem);
    else if (bid < 512)
        attn_body<16, 16, 16>(bid - 384, root, root, w_in + 5 * WI, b_in + 5 * BI,
                              Ors, (float*)smem);
    else if (bid < 576)
        leafp_mfma_body(bid - 512, inner, Wv0b, Wo0b, b_in, b_out, tP, smem);
    else
        mega3_body(bid - 576, leaf, inner, W1b, b_in + 1 * BI, W4kvb,
                   w_in + 4 * WI, b_in + 4 * BI, O1, Oc, smem);
}

// ---------------------------------------------------------------------------
// epilogue bodies (r10 verbatim)
// ---------------------------------------------------------------------------
__device__ void combleaf_body(int bid, const __bf16* __restrict__ O1,
                              const __bf16* __restrict__ Wob,
                              const float* __restrict__ Bo1,
                              const float* __restrict__ tP,
                              const float* __restrict__ wleaf,
                              float* __restrict__ out, char* __restrict__ sm)
{
    const int tid  = threadIdx.x;
    const int wid  = tid >> 6;
    const int lane = tid & 63;
    const int lr   = lane & 15;
    const int lk   = (lane >> 4) * 8;
    __bf16* Bs = (__bf16*)sm;           // [2][16][272]
    const int srow = tid >> 5;
    const int scol = (tid & 31) * 8;

    bf16x8 a[8];
    {
        const __bf16* ar = O1 + ((size_t)bid * 64 + wid * 16 + lr) * DIM + lk;
#pragma unroll
        for (int k = 0; k < 8; ++k) a[k] = *(const bf16x8*)(ar + k * 32);
    }
    const float e0 = __expf(wleaf[0]), e1 = __expf(wleaf[1]);
    const float wl0 = e0 / (e0 + e1), wl1 = e1 / (e0 + e1);
    const size_t row0 = (size_t)bid * 64 + wid * 16 + (lane >> 4) * 4;

    {
        bf16x8 g0 = *(const bf16x8*)(Wob + (size_t)srow * DIM + scol);
        bf16x8 g1 = *(const bf16x8*)(Wob + (size_t)(8 + srow) * DIM + scol);
        *(bf16x8*)(Bs + srow * 272 + scol) = g0;
        *(bf16x8*)(Bs + (8 + srow) * 272 + scol) = g1;
    }
    __syncthreads();

    for (int nt = 0; nt < 16; ++nt) {
        const int cur = nt & 1;
        const __bf16* Bc = Bs + cur * 4352;
        bf16x8 g0, g1;
        if (nt + 1 < 16) {
            const __bf16* p = Wob + (size_t)((nt + 1) * 16) * DIM;
            g0 = *(const bf16x8*)(p + (size_t)srow * DIM + scol);
            g1 = *(const bf16x8*)(p + (size_t)(8 + srow) * DIM + scol);
        }
        f32x4 acc = {0.f, 0.f, 0.f, 0.f};
#pragma unroll
        for (int k = 0; k < 8; ++k)
            acc = __builtin_amdgcn_mfma_f32_16x16x32_bf16(
                a[k], *(const bf16x8*)(Bc + lr * 272 + k * 32 + lk), acc, 0, 0, 0);
        const int   o  = nt * 16 + lr;
        const float bo = Bo1[o];
        const float tv = tP[(size_t)bid * DIM + o];
#pragma unroll
        for (int r = 0; r < 4; ++r)
            out[(row0 + r) * DIM + o] = wl0 * tv + wl1 * (acc[r] + bo);
        if (nt + 1 < 16) {
            __bf16* Bn = Bs + (cur ^ 1) * 4352;
            *(bf16x8*)(Bn + srow * 272 + scol) = g0;
            *(bf16x8*)(Bn + (8 + srow) * 272 + scol) = g1;
        }
        __syncthreads();
    }
}

__device__ void combine_inner_body(int vb, const float* __restrict__ Op,
    const float* __restrict__ Osf, const float* __restrict__ Oc,
    const float* __restrict__ W2, const float* __restrict__ B2,
    const float* __restrict__ W3, const float* __restrict__ B3,
    const float* __restrict__ W4, const float* __restrict__ B4,
    const float* __restrict__ winner, float* __restrict__ out, float* __restrict__ Ts)
{
    const int n0 = vb * 32;
    const int o  = threadIdx.x;
    const float e0 = __expf(winner[0]), e1 = __expf(winner[1]), e2 = __expf(winner[2]);
    const float inv = 1.f / (e0 + e1 + e2);
    const float wt0 = e0 * inv, wt1 = e1 * inv, wt2 = e2 * inv;

    float acc[32];
#pragma unroll
    for (int r = 0; r < 32; ++r) acc[r] = 0.f;
    const float biasacc = wt0 * B2[o] + wt1 * B3[o] + wt2 * B4[o];

#pragma unroll
    for (int term = 0; term < 3; ++term) {
        const float* Ob = (term == 0) ? Op : (term == 1) ? Osf : Oc;
        const float* Wb = (term == 0) ? W2 : (term == 1) ? W3 : W4;
        const float wt  = (term == 0) ? wt0 : (term == 1) ? wt1 : wt2;
        __syncthreads();
        for (int idx = threadIdx.x; idx < 32 * DIM; idx += 256)
            Ts[idx] = Ob[(size_t)n0 * DIM + idx];
        __syncthreads();
        const float4* wr = (const float4*)(Wb + (size_t)o * DIM);
        for (int k4 = 0; k4 < DIM / 4; ++k4) {
            float4 w = wr[k4];
            w.x *= wt; w.y *= wt; w.z *= wt; w.w *= wt;
#pragma unroll
            for (int r = 0; r < 32; ++r) {
                const float4 aa = *(const float4*)&Ts[r * DIM + k4 * 4];
                acc[r] += dot4(aa, w);
            }
        }
    }
#pragma unroll
    for (int r = 0; r < 32; ++r)
        out[(size_t)(n0 + r) * DIM + o] = acc[r] + biasacc;
}

__device__ void combine_root_body(int vb, const float* __restrict__ Ors,
    const float* __restrict__ Orc, const float* __restrict__ W5,
    const float* __restrict__ B5, const float* __restrict__ wroot,
    float* __restrict__ out, float* __restrict__ Ts)
{
    const int n0 = vb * 32;
    const int o  = threadIdx.x;
    const float e0 = __expf(wroot[0]), e1 = __expf(wroot[1]);
    const float w0 = e0 / (e0 + e1), w1 = e1 / (e0 + e1);
    for (int idx = threadIdx.x; idx < 32 * DIM; idx += 256)
        Ts[idx] = w0 * Ors[(size_t)n0 * DIM + idx] + w1 * Orc[(size_t)n0 * DIM + idx];
    __syncthreads();
    float acc[32];
#pragma unroll
    for (int r = 0; r < 32; ++r) acc[r] = 0.f;
    const float4* wr = (const float4*)(W5 + (size_t)o * DIM);
    for (int k4 = 0; k4 < DIM / 4; ++k4) {
        const float4 w = wr[k4];
#pragma unroll
        for (int r = 0; r < 32; ++r) {
            const float4 aa = *(const float4*)&Ts[r * DIM + k4 * 4];
            acc[r] += dot4(aa, w);
        }
    }
    const float bo = B5[o];
#pragma unroll
    for (int r = 0; r < 32; ++r)
        out[(size_t)(n0 + r) * DIM + o] = acc[r] + bo;
}

__global__ __launch_bounds__(256) void epilogue_kernel(
    const __bf16* __restrict__ O1, const __bf16* __restrict__ Wo1b,
    const float* __restrict__ w_out, const float* __restrict__ b_out,
    const float* __restrict__ tP, const float* __restrict__ Op,
    const float* __restrict__ Osf, const float* __restrict__ Oc,
    const float* __restrict__ Ors, const float* __restrict__ Orc,
    const float* __restrict__ wleaf, const float* __restrict__ winner,
    const float* __restrict__ wroot, float* __restrict__ out)
{
    extern __shared__ float smf[];
    const int bid = blockIdx.x;
    const size_t WO = 256 * 256, BO = 256;
    if (bid < 2048)
        combleaf_body(bid, O1, Wo1b, b_out + BO, tP, wleaf, out, (char*)smf);
    else if (bid < 2112)
        combine_inner_body(bid - 2048, Op, Osf, Oc,
                           w_out + 2 * WO, b_out + 2 * BO,
                           w_out + 3 * WO, b_out + 3 * BO,
                           w_out + 4 * WO, b_out + 4 * BO,
                           winner, out + 33554432, smf);
    else
        combine_root_body(bid - 2112, Ors, Orc, w_out + 5 * WO, b_out + 5 * BO,
                          wroot, out + 33554432 + 524288, smf);
}

// ---------------------------------------------------------------------------
extern "C" void kernel_launch(void* const* d_in, const int* in_sizes, int n_in,
                              void* d_out, int out_size, void* d_ws, size_t ws_size,
                              hipStream_t stream)
{
    const float* leaf   = (const float*)d_in[0];
    const float* inner  = (const float*)d_in[1];
    const float* root   = (const float*)d_in[2];
    const float* w_in   = (const float*)d_in[3];
    const float* b_in   = (const float*)d_in[4];
    const float* w_out  = (const float*)d_in[5];
    const float* b_out  = (const float*)d_in[6];
    const float* wleaf  = (const float*)d_in[7];
    const float* winner = (const float*)d_in[8];
    const float* wroot  = (const float*)d_in[9];
    float* out = (float*)d_out;

    const size_t WI = 768 * 256, WO = 256 * 256;

    // ws layout
    char* ws = (char*)d_ws;
    __bf16* W1b   = (__bf16*)(ws);                    // 393216 B
    __bf16* W4kvb = (__bf16*)(ws + 393216);           // 262144 B
    __bf16* Wo1b  = (__bf16*)(ws + 655360);           // 131072 B
    __bf16* Wv0b  = (__bf16*)(ws + 786432);           // 131072 B
    __bf16* Wo0b  = (__bf16*)(ws + 917504);           // 131072 B
    __bf16* O1b   = (__bf16*)(ws + 1048576);          // 67108864 B
    float*  tP    = (float*)(ws + 68157440);          // 2097152 B
    float*  Oc    = (float*)(ws + 70254592);
    float*  Op    = (float*)(ws + 72351744);
    float*  Osf   = (float*)(ws + 74448896);
    float*  Ors   = (float*)(ws + 76546048);
    float*  Orc   = (float*)(ws + 76808192);

    cvt_f2b<<<192, 256, 0, stream>>>(w_in + 1 * WI, W1b, 768 * 256);
    cvt_f2b<<<128, 256, 0, stream>>>(w_in + 4 * WI + 256 * 256, W4kvb, 512 * 256);
    cvt_f2b<<<64, 256, 0, stream>>>(w_out + 1 * WO, Wo1b, 256 * 256);
    cvt_f2b<<<64, 256, 0, stream>>>(w_in + 512 * 256, Wv0b, 256 * 256);
    cvt_f2b<<<64, 256, 0, stream>>>(w_out, Wo0b, 256 * 256);

    // fused main: aux (4 attn + leafp) + mega3 (2 tiles/block)
    fused_main<<<4672, 256, 79104, stream>>>(
        leaf, inner, root, w_in, b_in, b_out, W1b, W4kvb, Wv0b, Wo0b,
        O1b, Oc, tP, Op, Osf, Ors, Orc);

    // epilogue
    epilogue_kernel<<<2120, 256, 32768, stream>>>(O1b, Wo1b, w_out, b_out, tP,
                                                  Op, Osf, Oc, Ors, Orc,
                                                  wleaf, winner, wroot, out);
}

// Round 12
// 721.164 us; speedup vs baseline: 1.3078x; 1.3078x over previous
//
#include <hip/hip_runtime.h>
#include <hip/hip_bf16.h>
#include <cstdint>

// AttnLayerBU round 12: r8 (best: 729 us) + surgical fixes:
//   (1) nontemporal leaf loads + nontemporal O1 stores -> keep weights L2-hot
//   (2) Bs stride 264->272 in mega + combleaf (8-way -> 4-way bank conflicts)
// Everything else byte-identical to the passing r8.

#define DIM 256
#define NH 8
#define HD 32

static constexpr float SCALE = 0.17677669529663687f; // 32^-0.5

typedef __bf16 bf16x8 __attribute__((ext_vector_type(8)));
typedef __bf16 bf16x4 __attribute__((ext_vector_type(4)));
typedef float  f32x4  __attribute__((ext_vector_type(4)));

__device__ __forceinline__ float dot4(const float4 a, const float4 b) {
    return a.x * b.x + a.y * b.y + a.z * b.z + a.w * b.w;
}

// ---------------------------------------------------------------------------
__global__ __launch_bounds__(256) void cvt_f2b(const float* __restrict__ s,
                                               __bf16* __restrict__ d, int n) {
    int i = (blockIdx.x * 256 + threadIdx.x) * 4;
    if (i < n) {
        float4 v = *(const float4*)(s + i);
        d[i + 0] = (__bf16)v.x; d[i + 1] = (__bf16)v.y;
        d[i + 2] = (__bf16)v.z; d[i + 3] = (__bf16)v.w;
    }
}

// ---------------------------------------------------------------------------
// mega2 body (r8 structure)
// LDS (75008 B): Qs[64][72]@0  Ks@9216  Vt@18432  K4t@27648  V4t@36864
//   Pw 4x[16][72]@46080  scratch@55296(2304)  Bs[2][16][272]@57600 (17408)
// ---------------------------------------------------------------------------
__device__ void mega2_body(int g,
    const float* __restrict__ X, const float* __restrict__ inner,
    const __bf16* __restrict__ W1b, const float* __restrict__ Bi1,
    const __bf16* __restrict__ W4kvb, const float* __restrict__ W4q,
    const float* __restrict__ Bi4, __bf16* __restrict__ O1,
    float* __restrict__ Oc, char* __restrict__ smem)
{
    const int xcd  = g & 7;
    const int idx  = g >> 3;               // 0..1023
    const int b    = xcd * 256 + (idx >> 2);
    const int hg   = idx & 3;              // head-pair: heads 2hg, 2hg+1
    const int tid  = threadIdx.x;
    const int wid  = tid >> 6;             // 0..3
    const int lane = tid & 63;
    const int lr   = lane & 15;
    const int lk   = (lane >> 4) * 8;
    const int prow = (lane >> 4) * 4;
    const int tok0 = wid * 16 + prow;

    __bf16* Qs  = (__bf16*)smem;                    // [64][72]
    __bf16* Ks  = (__bf16*)(smem + 9216);
    __bf16* Vt  = (__bf16*)(smem + 18432);          // [64 d][72 tok]
    __bf16* K4t = (__bf16*)(smem + 27648);
    __bf16* V4t = (__bf16*)(smem + 36864);
    __bf16* Pw  = (__bf16*)(smem + 46080 + wid * 2304);  // wave-local [16][72]
    float* qpart = (float*)(smem + 55296);          // [4][64]
    float* qv    = qpart + 256;                     // [64]
    float* psm   = qv + 64;                         // [2][64]
    float* opart = psm + 128;                       // [2][64]
    __bf16* Bs  = (__bf16*)(smem + 57600);          // [2][16][272]

    // ---- A-fragments (NONTEMPORAL: don't evict weights from L2) ----
    bf16x8 a[8];
    {
        const float* xrow = X + ((size_t)b * 64 + wid * 16 + lr) * DIM + lk;
#pragma unroll
        for (int k = 0; k < 8; ++k) {
            const f32x4 v0 = __builtin_nontemporal_load((const f32x4*)(xrow + k * 32));
            const f32x4 v1 = __builtin_nontemporal_load((const f32x4*)(xrow + k * 32 + 4));
            bf16x8 t;
            t[0] = (__bf16)v0[0]; t[1] = (__bf16)v0[1]; t[2] = (__bf16)v0[2]; t[3] = (__bf16)v0[3];
            t[4] = (__bf16)v1[0]; t[5] = (__bf16)v1[1]; t[6] = (__bf16)v1[2]; t[7] = (__bf16)v1[3];
            a[k] = t;
        }
    }

    // ---- unified projection loop: 20 n-tiles, LDS double-buffered B ----
    {
        const int srow = tid >> 5;              // 0..7
        const int scol = (tid & 31) * 8;        // bf16 elems
        auto wsrc = [&](int t) -> const __bf16* {
            if (t < 12) {
                const int sec = t >> 2, sub = t & 3;
                return W1b + (size_t)(sec * 256 + hg * 64 + sub * 16) * DIM;
            }
            const int u = t - 12, sec = u >> 2, sub = u & 3;
            return W4kvb + (size_t)(sec * 256 + hg * 64 + sub * 16) * DIM;
        };
        {
            const __bf16* p = wsrc(0);
            bf16x8 g0 = *(const bf16x8*)(p + (size_t)srow * DIM + scol);
            bf16x8 g1 = *(const bf16x8*)(p + (size_t)(8 + srow) * DIM + scol);
            *(bf16x8*)(Bs + srow * 272 + scol) = g0;
            *(bf16x8*)(Bs + (8 + srow) * 272 + scol) = g1;
        }
        __syncthreads();

        for (int t = 0; t < 20; ++t) {
            const int cur = t & 1;
            const __bf16* Bc = Bs + cur * 4352;
            bf16x8 g0, g1;
            if (t + 1 < 20) {
                const __bf16* p = wsrc(t + 1);
                g0 = *(const bf16x8*)(p + (size_t)srow * DIM + scol);
                g1 = *(const bf16x8*)(p + (size_t)(8 + srow) * DIM + scol);
            }
            f32x4 aL = {0.f, 0.f, 0.f, 0.f}, aH = {0.f, 0.f, 0.f, 0.f};
#pragma unroll
            for (int kk = 0; kk < 4; ++kk) {
                const bf16x8 bL = *(const bf16x8*)(Bc + lr * 272 + kk * 32 + lk);
                aL = __builtin_amdgcn_mfma_f32_16x16x32_bf16(a[kk], bL, aL, 0, 0, 0);
            }
#pragma unroll
            for (int kk = 0; kk < 4; ++kk) {
                const bf16x8 bH = *(const bf16x8*)(Bc + lr * 272 + (kk + 4) * 32 + lk);
                aH = __builtin_amdgcn_mfma_f32_16x16x32_bf16(a[kk + 4], bH, aH, 0, 0, 0);
            }
            const f32x4 acc = aL + aH;
            const int sub = t & 3;
            const int col = sub * 16 + lr;
            if (t < 4) {
                const float bias = Bi1[hg * 64 + sub * 16 + lr];
#pragma unroll
                for (int r = 0; r < 4; ++r)
                    Qs[(size_t)(tok0 + r) * 72 + col] = (__bf16)((acc[r] + bias) * SCALE);
            } else if (t < 8) {
                const float bias = Bi1[256 + hg * 64 + sub * 16 + lr];
#pragma unroll
                for (int r = 0; r < 4; ++r)
                    Ks[(size_t)(tok0 + r) * 72 + col] = (__bf16)(acc[r] + bias);
            } else {
                bf16x4 pv;
                if (t < 12) {
                    const float bias = Bi1[512 + hg * 64 + sub * 16 + lr];
#pragma unroll
                    for (int r = 0; r < 4; ++r) pv[r] = (__bf16)(acc[r] + bias);
                    *(bf16x4*)(Vt + (size_t)col * 72 + tok0) = pv;
                } else if (t < 16) {
                    const float bias = Bi4[256 + hg * 64 + sub * 16 + lr];
#pragma unroll
                    for (int r = 0; r < 4; ++r) pv[r] = (__bf16)(acc[r] + bias);
                    *(bf16x4*)(K4t + (size_t)col * 72 + tok0) = pv;
                } else {
                    const float bias = Bi4[512 + hg * 64 + sub * 16 + lr];
#pragma unroll
                    for (int r = 0; r < 4; ++r) pv[r] = (__bf16)(acc[r] + bias);
                    *(bf16x4*)(V4t + (size_t)col * 72 + tok0) = pv;
                }
            }
            if (t + 1 < 20) {
                __bf16* Bn = Bs + (cur ^ 1) * 4352;
                *(bf16x8*)(Bn + srow * 272 + scol) = g0;
                *(bf16x8*)(Bn + (8 + srow) * 272 + scol) = g1;
            }
            __syncthreads();
        }
    }

    // ---- inner_c q-projection partials ----
    {
        const int o = tid & 63, part = tid >> 6;
        const float4* wr = (const float4*)(W4q + (size_t)(hg * 64 + o) * DIM + part * 64);
        const float4* xr = (const float4*)(inner + (size_t)b * DIM + part * 64);
        float accq = 0.f;
#pragma unroll
        for (int k = 0; k < 16; ++k) accq += dot4(xr[k], wr[k]);
        qpart[part * 64 + o] = accq;
    }
    __syncthreads();

    if (tid < 64)
        qv[tid] = (qpart[tid] + qpart[64 + tid] + qpart[128 + tid] + qpart[192 + tid]
                   + Bi4[hg * 64 + tid]) * SCALE;

    // ---- leaf_s attention: wave = (head hh, q-half qh) ----
    const int hh = wid >> 1;
    const int qh = wid & 1;
    f32x4 s[2][4];
    {
        bf16x8 kb[4];
#pragma unroll
        for (int kt = 0; kt < 4; ++kt)
            kb[kt] = *(const bf16x8*)(Ks + (size_t)(kt * 16 + lr) * 72 + hh * 32 + lk);
#pragma unroll
        for (int q2 = 0; q2 < 2; ++q2) {
            const int qt = qh * 2 + q2;
            const bf16x8 qa = *(const bf16x8*)(Qs + (size_t)(qt * 16 + lr) * 72 + hh * 32 + lk);
#pragma unroll
            for (int kt = 0; kt < 4; ++kt) {
                f32x4 z = {0.f, 0.f, 0.f, 0.f};
                s[q2][kt] = __builtin_amdgcn_mfma_f32_16x16x32_bf16(qa, kb[kt], z, 0, 0, 0);
            }
        }
    }
#pragma unroll
    for (int q2 = 0; q2 < 2; ++q2) {
#pragma unroll
        for (int r = 0; r < 4; ++r) {
            float m = fmaxf(fmaxf(s[q2][0][r], s[q2][1][r]), fmaxf(s[q2][2][r], s[q2][3][r]));
#pragma unroll
            for (int off = 1; off < 16; off <<= 1) m = fmaxf(m, __shfl_xor(m, off));
            const float p0 = __expf(s[q2][0][r] - m), p1 = __expf(s[q2][1][r] - m);
            const float p2 = __expf(s[q2][2][r] - m), p3 = __expf(s[q2][3][r] - m);
            float t = p0 + p1 + p2 + p3;
#pragma unroll
            for (int off = 1; off < 16; off <<= 1) t += __shfl_xor(t, off);
            const float inv = 1.0f / t;
            s[q2][0][r] = p0 * inv; s[q2][1][r] = p1 * inv;
            s[q2][2][r] = p2 * inv; s[q2][3][r] = p3 * inv;
        }
    }
    {
        bf16x8 vb[2][2];
#pragma unroll
        for (int dt = 0; dt < 2; ++dt)
#pragma unroll
            for (int ks = 0; ks < 2; ++ks)
                vb[dt][ks] = *(const bf16x8*)(Vt + (size_t)(hh * 32 + dt * 16 + lr) * 72 + ks * 32 + lk);
#pragma unroll
        for (int q2 = 0; q2 < 2; ++q2) {
            const int qt = qh * 2 + q2;
#pragma unroll
            for (int kt = 0; kt < 4; ++kt)
#pragma unroll
                for (int r = 0; r < 4; ++r)
                    Pw[(size_t)(prow + r) * 72 + kt * 16 + lr] = (__bf16)s[q2][kt][r];
            bf16x8 pa[2];
#pragma unroll
            for (int ks = 0; ks < 2; ++ks)
                pa[ks] = *(const bf16x8*)(Pw + (size_t)lr * 72 + ks * 32 + lk);
#pragma unroll
            for (int dt = 0; dt < 2; ++dt) {
                f32x4 o = {0.f, 0.f, 0.f, 0.f};
#pragma unroll
                for (int ks = 0; ks < 2; ++ks)
                    o = __builtin_amdgcn_mfma_f32_16x16x32_bf16(pa[ks], vb[dt][ks], o, 0, 0, 0);
                const int colO = (hg * 2 + hh) * 32 + dt * 16 + lr;
#pragma unroll
                for (int r = 0; r < 4; ++r)
                    __builtin_nontemporal_store((__bf16)o[r],
                        &O1[((size_t)b * 64 + qt * 16 + prow + r) * DIM + colO]);
            }
        }
    }
    __syncthreads();

    if (wid < 2) {
        const int j = lane;
        float sv = 0.f;
#pragma unroll
        for (int d = 0; d < 32; ++d)
            sv += qv[wid * 32 + d] * (float)K4t[(size_t)(wid * 32 + d) * 72 + j];
        float m = sv;
#pragma unroll
        for (int off = 1; off < 64; off <<= 1) m = fmaxf(m, __shfl_xor(m, off));
        const float p = __expf(sv - m);
        float t = p;
#pragma unroll
        for (int off = 1; off < 64; off <<= 1) t += __shfl_xor(t, off);
        psm[wid * 64 + j] = p / t;
    }
    __syncthreads();

    if (tid < 128) {
        const int o = tid & 63, hf = tid >> 6;
        const int ho = o >> 5;
        float acc2 = 0.f;
#pragma unroll
        for (int j = 0; j < 32; ++j)
            acc2 += psm[ho * 64 + hf * 32 + j] * (float)V4t[(size_t)o * 72 + hf * 32 + j];
        opart[hf * 64 + o] = acc2;
    }
    __syncthreads();
    if (tid < 64)
        Oc[(size_t)b * DIM + hg * 64 + tid] = opart[tid] + opart[64 + tid];
}

// ---------------------------------------------------------------------------
// leafp MFMA 2-stage (r8 verbatim): tP = (inner @ Wv0^T + bv0) @ Wo0^T + bo0
// LDS: tV[64][264]@0 (33792)  Bs[2][16][264]@33792 (16896)
// ---------------------------------------------------------------------------
__device__ void leafp_mfma_body(int bid, const float* __restrict__ inner,
    const __bf16* __restrict__ Wv0b, const __bf16* __restrict__ Wo0b,
    const float* __restrict__ b_in0, const float* __restrict__ b_out0,
    float* __restrict__ tP, char* __restrict__ smem)
{
    __bf16* tV = (__bf16*)smem;             // [64][264]
    __bf16* Bs = (__bf16*)(smem + 33792);   // [2][16][264]
    const int tid  = threadIdx.x;
    const int wid  = tid >> 6;
    const int lane = tid & 63;
    const int lr   = lane & 15;
    const int lk   = (lane >> 4) * 8;
    const int prow = (lane >> 4) * 4;
    const int tok0 = wid * 16 + prow;
    const int srow = tid >> 5;
    const int scol = (tid & 31) * 8;

    bf16x8 a[8];
    {
        const float* xrow = inner + ((size_t)bid * 64 + wid * 16 + lr) * DIM + lk;
#pragma unroll
        for (int k = 0; k < 8; ++k) {
            float4 v0 = *(const float4*)(xrow + k * 32);
            float4 v1 = *(const float4*)(xrow + k * 32 + 4);
            bf16x8 t;
            t[0] = (__bf16)v0.x; t[1] = (__bf16)v0.y; t[2] = (__bf16)v0.z; t[3] = (__bf16)v0.w;
            t[4] = (__bf16)v1.x; t[5] = (__bf16)v1.y; t[6] = (__bf16)v1.z; t[7] = (__bf16)v1.w;
            a[k] = t;
        }
    }

    {
        bf16x8 g0 = *(const bf16x8*)(Wv0b + (size_t)srow * DIM + scol);
        bf16x8 g1 = *(const bf16x8*)(Wv0b + (size_t)(8 + srow) * DIM + scol);
        *(bf16x8*)(Bs + srow * 264 + scol) = g0;
        *(bf16x8*)(Bs + (8 + srow) * 264 + scol) = g1;
    }
    __syncthreads();
    for (int t = 0; t < 16; ++t) {
        const int cur = t & 1;
        const __bf16* Bc = Bs + cur * 4224;
        bf16x8 g0, g1;
        if (t + 1 < 16) {
            const __bf16* p = Wv0b + (size_t)((t + 1) * 16) * DIM;
            g0 = *(const bf16x8*)(p + (size_t)srow * DIM + scol);
            g1 = *(const bf16x8*)(p + (size_t)(8 + srow) * DIM + scol);
        }
        f32x4 acc = {0.f, 0.f, 0.f, 0.f};
#pragma unroll
        for (int k = 0; k < 8; ++k)
            acc = __builtin_amdgcn_mfma_f32_16x16x32_bf16(
                a[k], *(const bf16x8*)(Bc + lr * 264 + k * 32 + lk), acc, 0, 0, 0);
        const float bias = b_in0[512 + t * 16 + lr];
#pragma unroll
        for (int r = 0; r < 4; ++r)
            tV[(size_t)(tok0 + r) * 264 + t * 16 + lr] = (__bf16)(acc[r] + bias);
        if (t + 1 < 16) {
            __bf16* Bn = Bs + (cur ^ 1) * 4224;
            *(bf16x8*)(Bn + srow * 264 + scol) = g0;
            *(bf16x8*)(Bn + (8 + srow) * 264 + scol) = g1;
        }
        __syncthreads();
    }

    bf16x8 a2[8];
#pragma unroll
    for (int k = 0; k < 8; ++k)
        a2[k] = *(const bf16x8*)(tV + (size_t)(wid * 16 + lr) * 264 + k * 32 + lk);
    {
        bf16x8 g0 = *(const bf16x8*)(Wo0b + (size_t)srow * DIM + scol);
        bf16x8 g1 = *(const bf16x8*)(Wo0b + (size_t)(8 + srow) * DIM + scol);
        *(bf16x8*)(Bs + srow * 264 + scol) = g0;
        *(bf16x8*)(Bs + (8 + srow) * 264 + scol) = g1;
    }
    __syncthreads();
    for (int t = 0; t < 16; ++t) {
        const int cur = t & 1;
        const __bf16* Bc = Bs + cur * 4224;
        bf16x8 g0, g1;
        if (t + 1 < 16) {
            const __bf16* p = Wo0b + (size_t)((t + 1) * 16) * DIM;
            g0 = *(const bf16x8*)(p + (size_t)srow * DIM + scol);
            g1 = *(const bf16x8*)(p + (size_t)(8 + srow) * DIM + scol);
        }
        f32x4 acc = {0.f, 0.f, 0.f, 0.f};
#pragma unroll
        for (int k = 0; k < 8; ++k)
            acc = __builtin_amdgcn_mfma_f32_16x16x32_bf16(
                a2[k], *(const bf16x8*)(Bc + lr * 264 + k * 32 + lk), acc, 0, 0, 0);
        const float bo = b_out0[t * 16 + lr];
#pragma unroll
        for (int r = 0; r < 4; ++r)
            tP[((size_t)bid * 64 + wid * 16 + prow + r) * DIM + t * 16 + lr] = acc[r] + bo;
        if (t + 1 < 16) {
            __bf16* Bn = Bs + (cur ^ 1) * 4224;
            *(bf16x8*)(Bn + srow * 264 + scol) = g0;
            *(bf16x8*)(Bn + (8 + srow) * 264 + scol) = g1;
        }
        __syncthreads();
    }
}

// ---------------------------------------------------------------------------
// fp32 fused attention body (r8 verbatim)
// ---------------------------------------------------------------------------
template <int LQ, int LK, int RQ>
__device__ void attn_body(int bx, const float* __restrict__ Xq,
                          const float* __restrict__ Xkv,
                          const float* __restrict__ Wi, const float* __restrict__ Bi,
                          float* __restrict__ O, float* __restrict__ sm)
{
    const int b   = bx >> 3;
    const int h   = bx & 7;
    const int tid = threadIdx.x;

    float* KsP = sm;                    // [LK][33]
    float* VsP = KsP + LK * 33;         // [LK][33]
    float* QsP = VsP + LK * 33;         // [LQ][33]
    float* SP  = QsP + LQ * 33;         // [RQ][LK+1]

    const float* xq  = Xq  + (size_t)b * LQ * DIM;
    const float* xkv = Xkv + (size_t)b * LK * DIM;

    {
        const int col   = tid & 63;
        const int which = col >> 5;
        const int d     = col & 31;
        const int row   = DIM + which * DIM + h * HD + d;
        const float4* wr = (const float4*)(Wi + (size_t)row * DIM);
        const float bias = Bi[row];
        constexpr int TT = LK / 4;
        float acc[TT];
#pragma unroll
        for (int i = 0; i < TT; ++i) acc[i] = 0.f;
        const int t0 = tid >> 6;
        for (int k4 = 0; k4 < DIM / 4; ++k4) {
            const float4 w = wr[k4];
#pragma unroll
            for (int i = 0; i < TT; ++i) {
                const int t = t0 + 4 * i;
                const float4 aa = ((const float4*)(xkv + (size_t)t * DIM))[k4];
                acc[i] += dot4(aa, w);
            }
        }
#pragma unroll
        for (int i = 0; i < TT; ++i) {
            const int t = t0 + 4 * i;
            if (which == 0) KsP[t * 33 + d] = acc[i] + bias;
            else            VsP[t * 33 + d] = acc[i] + bias;
        }
    }
    {
        constexpr int TGQ = (LQ >= 8) ? 8 : LQ;
        constexpr int TT  = LQ / TGQ;
        if (tid < 32 * TGQ) {
            const int d   = tid & 31;
            const int row = h * HD + d;
            const float4* wr = (const float4*)(Wi + (size_t)row * DIM);
            const float bias = Bi[row];
            float acc[TT];
#pragma unroll
            for (int i = 0; i < TT; ++i) acc[i] = 0.f;
            const int t0 = tid >> 5;
            for (int k4 = 0; k4 < DIM / 4; ++k4) {
                const float4 w = wr[k4];
#pragma unroll
                for (int i = 0; i < TT; ++i) {
                    const int t = t0 + TGQ * i;
                    const float4 aa = ((const float4*)(xq + (size_t)t * DIM))[k4];
                    acc[i] += dot4(aa, w);
                }
            }
#pragma unroll
            for (int i = 0; i < TT; ++i) {
                const int t = t0 + TGQ * i;
                QsP[t * 33 + d] = (acc[i] + bias) * SCALE;
            }
        }
    }
    __syncthreads();

    for (int q0 = 0; q0 < LQ; q0 += RQ) {
        for (int idx = tid; idx < RQ * LK; idx += 256) {
            const int r = idx / LK;
            const int j = idx - r * LK;
            float acc = 0.f;
#pragma unroll
            for (int d = 0; d < HD; ++d)
                acc += QsP[(q0 + r) * 33 + d] * KsP[j * 33 + d];
            SP[r * (LK + 1) + j] = acc;
        }
        __syncthreads();
        if (tid < RQ * 8) {
            const int r   = tid >> 3;
            const int sub = tid & 7;
            float m = -1e30f;
            for (int j = sub; j < LK; j += 8) m = fmaxf(m, SP[r * (LK + 1) + j]);
#pragma unroll
            for (int off = 4; off; off >>= 1) m = fmaxf(m, __shfl_xor(m, off, 8));
            float sum = 0.f;
            for (int j = sub; j < LK; j += 8) {
                const float p = __expf(SP[r * (LK + 1) + j] - m);
                SP[r * (LK + 1) + j] = p;
                sum += p;
            }
#pragma unroll
            for (int off = 4; off; off >>= 1) sum += __shfl_xor(sum, off, 8);
            const float inv = 1.0f / sum;
            for (int j = sub; j < LK; j += 8) SP[r * (LK + 1) + j] *= inv;
        }
        __syncthreads();
        for (int idx = tid; idx < RQ * HD; idx += 256) {
            const int r = idx >> 5;
            const int d = idx & 31;
            float acc = 0.f;
            for (int j = 0; j < LK; ++j)
                acc += SP[r * (LK + 1) + j] * VsP[j * 33 + d];
            O[((size_t)(b * LQ + q0 + r)) * DIM + h * HD + d] = acc;
        }
        __syncthreads();
    }
}

// ---------------------------------------------------------------------------
// fused_main (r8 dispatch layout)
// ---------------------------------------------------------------------------
__global__ __launch_bounds__(256, 2) void fused_main(
    const float* __restrict__ leaf, const float* __restrict__ inner,
    const float* __restrict__ root,
    const float* __restrict__ w_in, const float* __restrict__ b_in,
    const float* __restrict__ b_out,
    const __bf16* __restrict__ W1b, const __bf16* __restrict__ W4kvb,
    const __bf16* __restrict__ Wv0b, const __bf16* __restrict__ Wo0b,
    __bf16* __restrict__ O1, float* __restrict__ Oc, float* __restrict__ tP,
    float* __restrict__ Op, float* __restrict__ Osf,
    float* __restrict__ Ors, float* __restrict__ Orc)
{
    extern __shared__ __align__(16) char smem[];
    const int bid = blockIdx.x;
    const size_t WI = 768 * 256, BI = 768;
    if (bid < 128)
        attn_body<128, 128, 16>(bid, inner, inner, w_in + 3 * WI, b_in + 3 * BI,
                                Osf, (float*)smem);
    else if (bid < 256)
        attn_body<128, 16, 32>(bid - 128, inner, root, w_in + 2 * WI, b_in + 2 * BI,
                               Op, (float*)smem);
    else if (bid < 384)
        attn_body<16, 128, 16>(bid - 256, root, inner, w_in + 5 * WI, b_in + 5 * BI,
                               Orc, (float*)smem);
    else if (bid < 512)
        attn_body<16, 16, 16>(bid - 384, root, root, w_in + 5 * WI, b_in + 5 * BI,
                              Ors, (float*)smem);
    else if (bid < 544)
        leafp_mfma_body(bid - 512, inner, Wv0b, Wo0b, b_in, b_out, tP, smem);
    else
        mega2_body(bid - 544, leaf, inner, W1b, b_in + 1 * BI, W4kvb,
                   w_in + 4 * WI, b_in + 4 * BI, O1, Oc, smem);
}

// ---------------------------------------------------------------------------
// epilogue bodies (combleaf = r10-verified stride-272 version)
// ---------------------------------------------------------------------------
__device__ void combleaf_body(int bid, const __bf16* __restrict__ O1,
                              const __bf16* __restrict__ Wob,
                              const float* __restrict__ Bo1,
                              const float* __restrict__ tP,
                              const float* __restrict__ wleaf,
                              float* __restrict__ out, char* __restrict__ sm)
{
    const int tid  = threadIdx.x;
    const int wid  = tid >> 6;
    const int lane = tid & 63;
    const int lr   = lane & 15;
    const int lk   = (lane >> 4) * 8;
    __bf16* Bs = (__bf16*)sm;           // [2][16][272]
    const int srow = tid >> 5;
    const int scol = (tid & 31) * 8;

    bf16x8 a[8];
    {
        const __bf16* ar = O1 + ((size_t)bid * 64 + wid * 16 + lr) * DIM + lk;
#pragma unroll
        for (int k = 0; k < 8; ++k) a[k] = *(const bf16x8*)(ar + k * 32);
    }
    const float e0 = __expf(wleaf[0]), e1 = __expf(wleaf[1]);
    const float wl0 = e0 / (e0 + e1), wl1 = e1 / (e0 + e1);
    const size_t row0 = (size_t)bid * 64 + wid * 16 + (lane >> 4) * 4;

    {
        bf16x8 g0 = *(const bf16x8*)(Wob + (size_t)srow * DIM + scol);
        bf16x8 g1 = *(const bf16x8*)(Wob + (size_t)(8 + srow) * DIM + scol);
        *(bf16x8*)(Bs + srow * 272 + scol) = g0;
        *(bf16x8*)(Bs + (8 + srow) * 272 + scol) = g1;
    }
    __syncthreads();

    for (int nt = 0; nt < 16; ++nt) {
        const int cur = nt & 1;
        const __bf16* Bc = Bs + cur * 4352;
        bf16x8 g0, g1;
        if (nt + 1 < 16) {
            const __bf16* p = Wob + (size_t)((nt + 1) * 16) * DIM;
            g0 = *(const bf16x8*)(p + (size_t)srow * DIM + scol);
            g1 = *(const bf16x8*)(p + (size_t)(8 + srow) * DIM + scol);
        }
        f32x4 acc = {0.f, 0.f, 0.f, 0.f};
#pragma unroll
        for (int k = 0; k < 8; ++k)
            acc = __builtin_amdgcn_mfma_f32_16x16x32_bf16(
                a[k], *(const bf16x8*)(Bc + lr * 272 + k * 32 + lk), acc, 0, 0, 0);
        const int   o  = nt * 16 + lr;
        const float bo = Bo1[o];
        const float tv = tP[(size_t)bid * DIM + o];
#pragma unroll
        for (int r = 0; r < 4; ++r)
            out[(row0 + r) * DIM + o] = wl0 * tv + wl1 * (acc[r] + bo);
        if (nt + 1 < 16) {
            __bf16* Bn = Bs + (cur ^ 1) * 4352;
            *(bf16x8*)(Bn + srow * 272 + scol) = g0;
            *(bf16x8*)(Bn + (8 + srow) * 272 + scol) = g1;
        }
        __syncthreads();
    }
}

__device__ void combine_inner_body(int vb, const float* __restrict__ Op,
    const float* __restrict__ Osf, const float* __restrict__ Oc,
    const float* __restrict__ W2, const float* __restrict__ B2,
    const float* __restrict__ W3, const float* __restrict__ B3,
    const float* __restrict__ W4, const float* __restrict__ B4,
    const float* __restrict__ winner, float* __restrict__ out, float* __restrict__ Ts)
{
    const int n0 = vb * 32;
    const int o  = threadIdx.x;
    const float e0 = __expf(winner[0]), e1 = __expf(winner[1]), e2 = __expf(winner[2]);
    const float inv = 1.f / (e0 + e1 + e2);
    const float wt0 = e0 * inv, wt1 = e1 * inv, wt2 = e2 * inv;

    float acc[32];
#pragma unroll
    for (int r = 0; r < 32; ++r) acc[r] = 0.f;
    const float biasacc = wt0 * B2[o] + wt1 * B3[o] + wt2 * B4[o];

#pragma unroll
    for (int term = 0; term < 3; ++term) {
        const float* Ob = (term == 0) ? Op : (term == 1) ? Osf : Oc;
        const float* Wb = (term == 0) ? W2 : (term == 1) ? W3 : W4;
        const float wt  = (term == 0) ? wt0 : (term == 1) ? wt1 : wt2;
        __syncthreads();
        for (int idx = threadIdx.x; idx < 32 * DIM; idx += 256)
            Ts[idx] = Ob[(size_t)n0 * DIM + idx];
        __syncthreads();
        const float4* wr = (const float4*)(Wb + (size_t)o * DIM);
        for (int k4 = 0; k4 < DIM / 4; ++k4) {
            float4 w = wr[k4];
            w.x *= wt; w.y *= wt; w.z *= wt; w.w *= wt;
#pragma unroll
            for (int r = 0; r < 32; ++r) {
                const float4 aa = *(const float4*)&Ts[r * DIM + k4 * 4];
                acc[r] += dot4(aa, w);
            }
        }
    }
#pragma unroll
    for (int r = 0; r < 32; ++r)
        out[(size_t)(n0 + r) * DIM + o] = acc[r] + biasacc;
}

__device__ void combine_root_body(int vb, const float* __restrict__ Ors,
    const float* __restrict__ Orc, const float* __restrict__ W5,
    const float* __restrict__ B5, const float* __restrict__ wroot,
    float* __restrict__ out, float* __restrict__ Ts)
{
    const int n0 = vb * 32;
    const int o  = threadIdx.x;
    const float e0 = __expf(wroot[0]), e1 = __expf(wroot[1]);
    const float w0 = e0 / (e0 + e1), w1 = e1 / (e0 + e1);
    for (int idx = threadIdx.x; idx < 32 * DIM; idx += 256)
        Ts[idx] = w0 * Ors[(size_t)n0 * DIM + idx] + w1 * Orc[(size_t)n0 * DIM + idx];
    __syncthreads();
    float acc[32];
#pragma unroll
    for (int r = 0; r < 32; ++r) acc[r] = 0.f;
    const float4* wr = (const float4*)(W5 + (size_t)o * DIM);
    for (int k4 = 0; k4 < DIM / 4; ++k4) {
        const float4 w = wr[k4];
#pragma unroll
        for (int r = 0; r < 32; ++r) {
            const float4 aa = *(const float4*)&Ts[r * DIM + k4 * 4];
            acc[r] += dot4(aa, w);
        }
    }
    const float bo = B5[o];
#pragma unroll
    for (int r = 0; r < 32; ++r)
        out[(size_t)(n0 + r) * DIM + o] = acc[r] + bo;
}

__global__ __launch_bounds__(256) void epilogue_kernel(
    const __bf16* __restrict__ O1, const __bf16* __restrict__ Wo1b,
    const float* __restrict__ w_out, const float* __restrict__ b_out,
    const float* __restrict__ tP, const float* __restrict__ Op,
    const float* __restrict__ Osf, const float* __restrict__ Oc,
    const float* __restrict__ Ors, const float* __restrict__ Orc,
    const float* __restrict__ wleaf, const float* __restrict__ winner,
    const float* __restrict__ wroot, float* __restrict__ out)
{
    extern __shared__ float smf[];
    const int bid = blockIdx.x;
    const size_t WO = 256 * 256, BO = 256;
    if (bid < 2048)
        combleaf_body(bid, O1, Wo1b, b_out + BO, tP, wleaf, out, (char*)smf);
    else if (bid < 2112)
        combine_inner_body(bid - 2048, Op, Osf, Oc,
                           w_out + 2 * WO, b_out + 2 * BO,
                           w_out + 3 * WO, b_out + 3 * BO,
                           w_out + 4 * WO, b_out + 4 * BO,
                           winner, out + 33554432, smf);
    else
        combine_root_body(bid - 2112, Ors, Orc, w_out + 5 * WO, b_out + 5 * BO,
                          wroot, out + 33554432 + 524288, smf);
}

// ---------------------------------------------------------------------------
extern "C" void kernel_launch(void* const* d_in, const int* in_sizes, int n_in,
                              void* d_out, int out_size, void* d_ws, size_t ws_size,
                              hipStream_t stream)
{
    const float* leaf   = (const float*)d_in[0];
    const float* inner  = (const float*)d_in[1];
    const float* root   = (const float*)d_in[2];
    const float* w_in   = (const float*)d_in[3];
    const float* b_in   = (const float*)d_in[4];
    const float* w_out  = (const float*)d_in[5];
    const float* b_out  = (const float*)d_in[6];
    const float* wleaf  = (const float*)d_in[7];
    const float* winner = (const float*)d_in[8];
    const float* wroot  = (const float*)d_in[9];
    float* out = (float*)d_out;

    const size_t WI = 768 * 256, WO = 256 * 256;

    // ws layout
    char* ws = (char*)d_ws;
    __bf16* W1b   = (__bf16*)(ws);                    // 393216 B
    __bf16* W4kvb = (__bf16*)(ws + 393216);           // 262144 B
    __bf16* Wo1b  = (__bf16*)(ws + 655360);           // 131072 B
    __bf16* Wv0b  = (__bf16*)(ws + 786432);           // 131072 B
    __bf16* Wo0b  = (__bf16*)(ws + 917504);           // 131072 B
    __bf16* O1b   = (__bf16*)(ws + 1048576);          // 67108864 B
    float*  tP    = (float*)(ws + 68157440);          // 2097152 B
    float*  Oc    = (float*)(ws + 70254592);
    float*  Op    = (float*)(ws + 72351744);
    float*  Osf   = (float*)(ws + 74448896);
    float*  Ors   = (float*)(ws + 76546048);
    float*  Orc   = (float*)(ws + 76808192);

    cvt_f2b<<<192, 256, 0, stream>>>(w_in + 1 * WI, W1b, 768 * 256);
    cvt_f2b<<<128, 256, 0, stream>>>(w_in + 4 * WI + 256 * 256, W4kvb, 512 * 256);
    cvt_f2b<<<64, 256, 0, stream>>>(w_out + 1 * WO, Wo1b, 256 * 256);
    cvt_f2b<<<64, 256, 0, stream>>>(w_in + 512 * 256, Wv0b, 256 * 256);
    cvt_f2b<<<64, 256, 0, stream>>>(w_out, Wo0b, 256 * 256);

    // fused main: aux (4 attn + leafp-MFMA) + mega2 (r8 layout, 75008 B LDS)
    fused_main<<<8736, 256, 75008, stream>>>(
        leaf, inner, root, w_in, b_in, b_out, W1b, W4kvb, Wv0b, Wo0b,
        O1b, Oc, tP, Op, Osf, Ors, Orc);

    // epilogue: combleaf + combine_inner + combine_root
    epilogue_kernel<<<2120, 256, 32768, stream>>>(O1b, Wo1b, w_out, b_out, tP,
                                                  Op, Osf, Oc, Ors, Orc,
                                                  wleaf, winner, wroot, out);
}